// Round 10
// baseline (213.158 us; speedup 1.0000x reference)
//
#include <hip/hip_runtime.h>
#include <hip/hip_bf16.h>

#define HID 256
#define NROWS 2048
#define GRID (NROWS / 8)        // 256 blocks x 512 threads; 8 waves, 1 n-row/wave

typedef __attribute__((ext_vector_type(8))) short short8;   // 8 bf16 (MFMA A/B frag)
typedef __attribute__((ext_vector_type(4))) float float4v;
typedef __attribute__((ext_vector_type(4))) unsigned int uint4v;

__device__ __forceinline__ unsigned int pk_bf16(float a, float b) {
    __hip_bfloat162 p = __float22bfloat162_rn(float2{a, b});  // v_cvt_pk_bf16_f32
    return *(unsigned int*)&p;
}

// tanh via 1 exp2 + 1 rcp (2 trans ops total)
__device__ __forceinline__ float tanh_fast(float y) {
    const float E  = __builtin_amdgcn_exp2f(y * 2.8853900817779268f);  // e^(2y)
    const float rd = __builtin_amdgcn_rcpf(E + 1.0f);
    return __builtin_fmaf(-2.0f, rd, 1.0f);
}

// exp(s) for |s| <= 1/16 (|ctx|<=1/16 bounds it): 3-FMA Taylor, err ~6e-7.
// Replaces a 3rd transcendental (R0-proven numerics, same absmax).
__device__ __forceinline__ float exp_small(float s) {
    float p = __builtin_fmaf(s, 0.16666667f, 0.5f);
    p = __builtin_fmaf(p, s, 1.0f);
    return __builtin_fmaf(p, s, 1.0f);
}

// sum across each 16-lane DPP row (VALU pipe, no LDS)
__device__ __forceinline__ float row16_sum(float v) {
    float t;
    t = __builtin_bit_cast(float, __builtin_amdgcn_update_dpp(
            0, __builtin_bit_cast(int, v), 0xB1, 0xf, 0xf, true));  // quad_perm(1,0,3,2)
    v += t;
    t = __builtin_bit_cast(float, __builtin_amdgcn_update_dpp(
            0, __builtin_bit_cast(int, v), 0x4E, 0xf, 0xf, true));  // quad_perm(2,3,0,1)
    v += t;
    t = __builtin_bit_cast(float, __builtin_amdgcn_update_dpp(
            0, __builtin_bit_cast(int, v), 0x124, 0xf, 0xf, true)); // row_ror:4
    v += t;
    t = __builtin_bit_cast(float, __builtin_amdgcn_update_dpp(
            0, __builtin_bit_cast(int, v), 0x128, 0xf, 0xf, true)); // row_ror:8
    v += t;
    return v;
}

// Wave-independent design (validated R9: passes, no spill, zero main-loop
// barriers). R10 deltas:
//   1. epilogue 3 trans -> 2 (tanh_fast + exp_small Taylor, R0 numerics)
//   2. chunk-ahead double staging stA/stB: each half's loads issued one FULL
//      chunk before use -> vmcnt waits satisfied-on-arrival, vmem queue never
//      drains between GEMM/epilogue phases. (+32 regs, ~212 < 256 cap)
//   3. both chunk-0 halves issued before W staging.
__global__ __launch_bounds__(512, 1) void attend_fused(
    const float* __restrict__ x, const float* __restrict__ W,
    const float* __restrict__ bias, const float* __restrict__ ctx,
    float* __restrict__ out)
{
    __shared__ unsigned short Wb[256 * 256];   // 128 KB, [col][k] bf16, swizzled
    __shared__ float btab[256];                // bias
    __shared__ float ftab[256];                // ctx (raw; Taylor takes ctx*t)

    const int tid  = threadIdx.x;
    const int wave = tid >> 6;    // 0..7
    const int lane = tid & 63;
    const int q    = lane >> 4;   // quad 0..3
    const int c    = lane & 15;
    const int n    = blockIdx.x * 8 + wave;
    const float* xn = x + (size_t)n * (64 * 256);

    // ---- issue BOTH chunk-0 halves first; they land under W staging ----
    // A-frag layout: lane (c,q) holds x[word c][k = kt*32 + q*8 + j]
    float4v stA[8], stB[8];       // 2 x 32 VGPR staging (kt-halves of 16 rows)
    {
        const float* xr = xn + c * 256 + q * 8;
#pragma unroll
        for (int k2 = 0; k2 < 4; ++k2) {
            stA[2 * k2]     = *(const float4v*)(xr + k2 * 32);
            stA[2 * k2 + 1] = *(const float4v*)(xr + k2 * 32 + 4);
        }
#pragma unroll
        for (int k2 = 0; k2 < 4; ++k2) {
            stB[2 * k2]     = *(const float4v*)(xr + (k2 + 4) * 32);
            stB[2 * k2 + 1] = *(const float4v*)(xr + (k2 + 4) * 32 + 4);
        }
    }

    // ---- stage W (f32 -> bf16) into swizzled LDS; W is L2/L3-resident ----
    {
        char* wbb = (char*)Wb;
#pragma unroll 4
        for (int i = 0; i < 32; ++i) {
            const int f4  = tid + 512 * i;        // 0..16383 float4 chunks
            const int col = f4 >> 6;              // W output-col (0..255)
            const int k4  = (f4 & 63) * 4;        // k position (floats)
            float4v v = *((const float4v*)W + f4);
            uint2 u;
            u.x = pk_bf16(v.x, v.y);
            u.y = pk_bf16(v.z, v.w);
            const int byte = (col * 512 + k4 * 2) ^ ((col & 7) << 4);  // T2 swizzle
            *(uint2*)(wbb + byte) = u;
        }
        if (tid < 256) {
            btab[tid] = bias[tid];
            ftab[tid] = ctx[tid];
        }
    }

    // ---- identity B-fragments: mfma(xfrag[nt>>1], ifr[nt&1]) = x in D-layout
    // I[k][col] = 1 iff k == p*16 + col ; lane holds B[k=q*8+j][col=c]
    short8 ifr[2];
#pragma unroll
    for (int p = 0; p < 2; ++p) {
        short8 f = (short8){0, 0, 0, 0, 0, 0, 0, 0};
#pragma unroll
        for (int j = 0; j < 8; ++j)
            f[j] = (q * 8 + j == p * 16 + c) ? (short)0x3F80 : (short)0;
        ifr[p] = f;
    }

    // ---- loop-invariant swizzled read bases: XOR over FULL k-offset (R3 fix)
    int swzbase[8];
#pragma unroll
    for (int kt = 0; kt < 8; ++kt)
        swzbase[kt] = c * 512 + ((kt * 64 + q * 16) ^ ((c & 7) << 4));

    __syncthreads();   // the ONLY block barrier: Wb/btab/ftab ready

    const char* wbb = (const char*)Wb;

    float oacc[16];
#pragma unroll
    for (int nt = 0; nt < 16; ++nt) oacc[nt] = 0.f;

#pragma unroll 1
    for (int ch = 0; ch < 4; ++ch) {   // 4 chunks x 16 words = 64 words
        // Memory clobber: keeps btab/ftab re-read per iteration (not
        // loop-carried regs) and anchors previously-issued prefetch loads.
        asm volatile("" ::: "memory");

        short8 xfrag[8];

        // ---- cvt half-0 from stA (loads issued one full chunk ago) ----
#pragma unroll
        for (int k2 = 0; k2 < 4; ++k2) {
            uint4v u = { pk_bf16(stA[2 * k2].x,     stA[2 * k2].y),
                         pk_bf16(stA[2 * k2].z,     stA[2 * k2].w),
                         pk_bf16(stA[2 * k2 + 1].x, stA[2 * k2 + 1].y),
                         pk_bf16(stA[2 * k2 + 1].z, stA[2 * k2 + 1].w) };
            xfrag[k2] = __builtin_bit_cast(short8, u);
        }
        // ---- issue chunk ch+1 half-0 into stA: a full chunk of flight time ----
        if (ch < 3) {
            const float* xr = xn + ((ch + 1) * 16 + c) * 256 + q * 8;
#pragma unroll
            for (int k2 = 0; k2 < 4; ++k2) {
                stA[2 * k2]     = *(const float4v*)(xr + k2 * 32);
                stA[2 * k2 + 1] = *(const float4v*)(xr + k2 * 32 + 4);
            }
        }

        // ---- GEMM half-0: kt 0..3 x 256 cols, B from swizzled LDS ----
        float4v acc[16];
#pragma unroll
        for (int nt = 0; nt < 16; ++nt) acc[nt] = (float4v){0.f, 0.f, 0.f, 0.f};
#pragma unroll
        for (int kt = 0; kt < 4; ++kt) {
#pragma unroll
            for (int nt = 0; nt < 16; ++nt) {
                const short8 b = *(const short8*)(wbb + (swzbase[kt] + nt * 8192));
                acc[nt] = __builtin_amdgcn_mfma_f32_16x16x32_bf16(
                    xfrag[kt], b, acc[nt], 0, 0, 0);
            }
        }

        // ---- cvt half-1 from stB (issued one full chunk ago) ----
#pragma unroll
        for (int k2 = 0; k2 < 4; ++k2) {
            uint4v u = { pk_bf16(stB[2 * k2].x,     stB[2 * k2].y),
                         pk_bf16(stB[2 * k2].z,     stB[2 * k2].w),
                         pk_bf16(stB[2 * k2 + 1].x, stB[2 * k2 + 1].y),
                         pk_bf16(stB[2 * k2 + 1].z, stB[2 * k2 + 1].w) };
            xfrag[4 + k2] = __builtin_bit_cast(short8, u);
        }
        // ---- issue chunk ch+1 half-1 into stB ----
        if (ch < 3) {
            const float* xr = xn + ((ch + 1) * 16 + c) * 256 + q * 8;
#pragma unroll
            for (int k2 = 0; k2 < 4; ++k2) {
                stB[2 * k2]     = *(const float4v*)(xr + (k2 + 4) * 32);
                stB[2 * k2 + 1] = *(const float4v*)(xr + (k2 + 4) * 32 + 4);
            }
        }

        // ---- GEMM half-1: kt 4..7 ----
#pragma unroll
        for (int kt = 4; kt < 8; ++kt) {
#pragma unroll
            for (int nt = 0; nt < 16; ++nt) {
                const short8 b = *(const short8*)(wbb + (swzbase[kt] + nt * 8192));
                acc[nt] = __builtin_amdgcn_mfma_f32_16x16x32_bf16(
                    xfrag[kt], b, acc[nt], 0, 0, 0);
            }
        }

        // ---- epilogue: e = exp(ctx*tanh(y)); 2 trans/elem (R0 numerics) ----
        // D layout: row = word = q*4 + r (per mt... here 16 rows), col = nt*16+c
        float psum[4] = {0.f, 0.f, 0.f, 0.f};
#pragma unroll
        for (int nt = 0; nt < 16; ++nt) {
            const float bb = btab[nt * 16 + c];
            const float ff = ftab[nt * 16 + c];
#pragma unroll
            for (int r = 0; r < 4; ++r) {
                const float t = tanh_fast(acc[nt][r] + bb);
                const float e = exp_small(ff * t);
                acc[nt][r] = e;
                psum[r] += e;
            }
        }
        // ---- wave-local softmax denominators: DPP sum over the 16 c-lanes ----
        float rinv[4];
#pragma unroll
        for (int r = 0; r < 4; ++r)
            rinv[r] = __builtin_amdgcn_rcpf(row16_sum(psum[r]));

        // ---- final: out += x*e*rinv; x recovered in D-layout via identity MFMA
        const float4v zero4 = {0.f, 0.f, 0.f, 0.f};
#pragma unroll
        for (int nt = 0; nt < 16; ++nt) {
            float4v xD = __builtin_amdgcn_mfma_f32_16x16x32_bf16(
                xfrag[nt >> 1], ifr[nt & 1], zero4, 0, 0, 0);
#pragma unroll
            for (int r = 0; r < 4; ++r)
                oacc[nt] += xD[r] * (acc[nt][r] * rinv[r]);
        }
    }

    // ---- cross-q reduce (words are split across q-groups) + store ----
#pragma unroll
    for (int nt = 0; nt < 16; ++nt) {
        float v = oacc[nt];
        v += __shfl_xor(v, 16);
        v += __shfl_xor(v, 32);
        oacc[nt] = v;
    }
    if (q == 0) {
#pragma unroll
        for (int nt = 0; nt < 16; ++nt)
            out[(size_t)n * HID + nt * 16 + c] = oacc[nt];
    }
}

extern "C" void kernel_launch(void* const* d_in, const int* in_sizes, int n_in,
                              void* d_out, int out_size, void* d_ws, size_t ws_size,
                              hipStream_t stream) {
    const float* x    = (const float*)d_in[0];   // [2048, 64, 256] f32
    const float* W    = (const float*)d_in[1];   // [256, 256] f32
    const float* bias = (const float*)d_in[2];   // [256]
    const float* ctx  = (const float*)d_in[3];   // [256]
    (void)in_sizes; (void)n_in; (void)d_ws; (void)ws_size;

    attend_fused<<<GRID, 512, 0, stream>>>(x, W, bias, ctx, (float*)d_out);
}